// Round 6
// baseline (65.818 us; speedup 1.0000x reference)
//
#include <hip/hip_runtime.h>

#define F_   128
#define H_   16
#define E_   32
#define FG   8     // features per wave
#define BPW  64    // b rows per wave
#define WAVES 4
#define NTHREADS (WAVES * 64)   // 256

typedef float v4f __attribute__((ext_vector_type(4)));

// R2 structure (best: 56.7 us) with ONE change: plain stores instead of
// nontemporal. Theory: nt store acks come from the HBM/fabric side (~1 us),
// and with ~1 store in flight per wave (compiler vmcnt), Little's law caps
// effective write BW at ~4.7 TB/s — exactly what R2 measured. Plain stores
// ack at L2 (~300 cyc); L2 (4 MB/XCD) absorbs and drains the stream, as the
// harness's fill kernel demonstrates at 7 TB/s.
__global__ __launch_bounds__(NTHREADS, 4)
void nfe_kernel(const float* __restrict__ x,
                const float* __restrict__ W1,
                const float* __restrict__ b1,
                const float* __restrict__ W2,
                const float* __restrict__ b2,
                float* __restrict__ out)
{
    const int tid  = threadIdx.x;
    const int wave = tid >> 6;
    const int lane = tid & 63;

    const int f0 = blockIdx.x * FG;
    const int b0 = (blockIdx.y * WAVES + wave) * BPW;

    const int f  = f0 + (lane >> 3);
    const int e4 = lane & 7;

    // ---- per-lane weight fragments in registers ----
    float w1v[H_], b1v[H_];
    {
        const v4f* p1 = (const v4f*)(W1 + f * H_);
        const v4f* p2 = (const v4f*)(b1 + f * H_);
#pragma unroll
        for (int q = 0; q < 4; ++q) {
            v4f a = p1[q], c = p2[q];
            w1v[q*4+0]=a.x; w1v[q*4+1]=a.y; w1v[q*4+2]=a.z; w1v[q*4+3]=a.w;
            b1v[q*4+0]=c.x; b1v[q*4+1]=c.y; b1v[q*4+2]=c.z; b1v[q*4+3]=c.w;
        }
    }
    v4f w2v[H_];
#pragma unroll
    for (int j = 0; j < H_; ++j)
        w2v[j] = *(const v4f*)(W2 + (f * H_ + j) * E_ + e4 * 4);
    const v4f b2v = *(const v4f*)(b2 + f * E_ + e4 * 4);

    // ---- streaming loop over b ----
    const float* xp = x + (size_t)b0 * F_ + f;
    v4f* op = (v4f*)out + (size_t)b0 * (F_ * E_ / 4)
            + f0 * (E_ / 4) + lane;

    float xv_next = *xp;
#pragma unroll 2
    for (int i = 0; i < BPW; ++i) {
        const float xv = xv_next;
        if (i + 1 < BPW) xv_next = xp[(i + 1) * F_];   // prefetch next b

        v4f acc = b2v;
#pragma unroll
        for (int j = 0; j < H_; ++j) {
            const float hj = fmaxf(fmaf(xv, w1v[j], b1v[j]), 0.0f);
            acc.x = fmaf(hj, w2v[j].x, acc.x);
            acc.y = fmaf(hj, w2v[j].y, acc.y);
            acc.z = fmaf(hj, w2v[j].z, acc.z);
            acc.w = fmaf(hj, w2v[j].w, acc.w);
        }
        op[i * (F_ * E_ / 4)] = acc;   // plain store -> L2 write-back path
    }
}

extern "C" void kernel_launch(void* const* d_in, const int* in_sizes, int n_in,
                              void* d_out, int out_size, void* d_ws, size_t ws_size,
                              hipStream_t stream) {
    const float* x  = (const float*)d_in[0];
    const float* W1 = (const float*)d_in[1];
    const float* b1 = (const float*)d_in[2];
    const float* W2 = (const float*)d_in[3];
    const float* b2 = (const float*)d_in[4];
    float* out = (float*)d_out;

    const int B = in_sizes[0] / F_;                 // 16384
    dim3 grid(F_ / FG, B / (BPW * WAVES));          // (16, 64)
    nfe_kernel<<<grid, NTHREADS, 0, stream>>>(x, W1, b1, W2, b2, out);
}

// Round 7
// 55.025 us; speedup vs baseline: 1.1962x; 1.1962x over previous
//
#include <hip/hip_runtime.h>

#define F_   128
#define H_   16
#define E_   32
#define FG   8     // features per wave
#define BPW  64    // b rows per wave
#define WAVES 4
#define NTHREADS (WAVES * 64)   // 256

typedef float v2f __attribute__((ext_vector_type(2)));
typedef float v4f __attribute__((ext_vector_type(4)));

// R2 champion structure (56.7 us) with ONE change: packed-fp32 math.
// Layer1: 8x v_pk_fma_f32 + 8x pk max  (h computed in pairs).
// Layer2: 32x v_pk_fma_f32 using op_sel to broadcast h.lo / h.hi -> no movs.
// Per-iter VALU ~96 -> ~50 inst. j-ascending accumulation order preserved ->
// bit-identical to R2. Tests the "VALU serializes with store stream" model.
__global__ __launch_bounds__(NTHREADS, 4)
void nfe_kernel(const float* __restrict__ x,
                const float* __restrict__ W1,
                const float* __restrict__ b1,
                const float* __restrict__ W2,
                const float* __restrict__ b2,
                float* __restrict__ out)
{
    const int tid  = threadIdx.x;
    const int wave = tid >> 6;
    const int lane = tid & 63;

    const int f0 = blockIdx.x * FG;
    const int b0 = (blockIdx.y * WAVES + wave) * BPW;

    const int f  = f0 + (lane >> 3);
    const int e4 = lane & 7;

    // ---- per-lane weight fragments in registers (as f32 pairs) ----
    v2f w1p[H_/2], b1p[H_/2];
    {
        const v2f* p1 = (const v2f*)(W1 + f * H_);
        const v2f* p2 = (const v2f*)(b1 + f * H_);
#pragma unroll
        for (int q = 0; q < H_/2; ++q) { w1p[q] = p1[q]; b1p[q] = p2[q]; }
    }
    v2f w2p[H_][2];   // [j][e-pair], e-pair covers this lane's 4 e's
#pragma unroll
    for (int j = 0; j < H_; ++j) {
        const v2f* q = (const v2f*)(W2 + (f * H_ + j) * E_ + e4 * 4);
        w2p[j][0] = q[0]; w2p[j][1] = q[1];
    }
    v2f b2p[2];
    {
        const v2f* q = (const v2f*)(b2 + f * E_ + e4 * 4);
        b2p[0] = q[0]; b2p[1] = q[1];
    }

    // ---- streaming loop over b ----
    const float* xp = x + (size_t)b0 * F_ + f;
    v4f* op = (v4f*)out + (size_t)b0 * (F_ * E_ / 4)
            + f0 * (E_ / 4) + lane;

    const v2f zero2 = {0.0f, 0.0f};

    float xv_next = *xp;
#pragma unroll 2
    for (int i = 0; i < BPW; ++i) {
        const float xv = xv_next;
        if (i + 1 < BPW) xv_next = xp[(i + 1) * F_];   // prefetch next b

        // layer 1: h pairs
        v2f x2 = {xv, xv};
        v2f h2[H_/2];
#pragma unroll
        for (int q = 0; q < H_/2; ++q) {
            v2f t = __builtin_elementwise_fma(x2, w1p[q], b1p[q]);
            h2[q] = __builtin_elementwise_max(t, zero2);
        }

        // layer 2: acc pairs, h broadcast via op_sel (lo then hi of h2[q])
        v2f a0 = b2p[0], a1 = b2p[1];
#pragma unroll
        for (int q = 0; q < H_/2; ++q) {
            // j = 2q   (broadcast h2[q].lo)
            asm("v_pk_fma_f32 %0, %1, %2, %0 op_sel:[0,0,0] op_sel_hi:[0,1,1]"
                : "+v"(a0) : "v"(h2[q]), "v"(w2p[2*q][0]));
            asm("v_pk_fma_f32 %0, %1, %2, %0 op_sel:[0,0,0] op_sel_hi:[0,1,1]"
                : "+v"(a1) : "v"(h2[q]), "v"(w2p[2*q][1]));
            // j = 2q+1 (broadcast h2[q].hi)
            asm("v_pk_fma_f32 %0, %1, %2, %0 op_sel:[1,0,0] op_sel_hi:[1,1,1]"
                : "+v"(a0) : "v"(h2[q]), "v"(w2p[2*q+1][0]));
            asm("v_pk_fma_f32 %0, %1, %2, %0 op_sel:[1,0,0] op_sel_hi:[1,1,1]"
                : "+v"(a1) : "v"(h2[q]), "v"(w2p[2*q+1][1]));
        }

        v4f acc = {a0.x, a0.y, a1.x, a1.y};
        __builtin_nontemporal_store(acc, op + i * (F_ * E_ / 4));
    }
}

extern "C" void kernel_launch(void* const* d_in, const int* in_sizes, int n_in,
                              void* d_out, int out_size, void* d_ws, size_t ws_size,
                              hipStream_t stream) {
    const float* x  = (const float*)d_in[0];
    const float* W1 = (const float*)d_in[1];
    const float* b1 = (const float*)d_in[2];
    const float* W2 = (const float*)d_in[3];
    const float* b2 = (const float*)d_in[4];
    float* out = (float*)d_out;

    const int B = in_sizes[0] / F_;                 // 16384
    dim3 grid(F_ / FG, B / (BPW * WAVES));          // (16, 64)
    nfe_kernel<<<grid, NTHREADS, 0, stream>>>(x, W1, b1, W2, b2, out);
}